// Round 10
// baseline (167.614 us; speedup 1.0000x reference)
//
#include <hip/hip_runtime.h>

#define D 128
#define CAP 32
#define EPT 8          // edges per thread in bucket blocks
#define NEG_SLOPE 0.01f

typedef float v4f __attribute__((ext_vector_type(4)));
typedef short short8 __attribute__((ext_vector_type(8)));

static __device__ __forceinline__ short f2bf(float f) {
    unsigned u = __float_as_uint(f);
    unsigned r = (u + 0x7fffu + ((u >> 16) & 1u)) >> 16;   // round-nearest-even
    return (short)r;
}
static __device__ __forceinline__ float bflo(unsigned u) { return __uint_as_float(u << 16); }
static __device__ __forceinline__ float bfhi(unsigned u) { return __uint_as_float(u & 0xffff0000u); }
static __device__ __forceinline__ unsigned packbf(float x, float y) {
    return (unsigned)(unsigned short)f2bf(x) | ((unsigned)(unsigned short)f2bf(y) << 16);
}
static __device__ __forceinline__ float lrelu(float v) {
    return (v >= 0.0f) ? v : NEG_SLOPE * v;
}

// -------- fused, block-specialized: bucket blocks + conv blocks ------------
// blocks [0, nbB)      : bucket fill, EPT edges/thread INTERLEAVED (coalesced)
// blocks [nbB, ...)    : fp32->bf16 conversion stream (features + W)
__global__ __launch_bounds__(256) void convbucket_kernel(const float* __restrict__ feat,
                                                         const float* __restrict__ W1,
                                                         const float* __restrict__ W2,
                                                         const int* __restrict__ tgt,
                                                         const int* __restrict__ nbr,
                                                         const float* __restrict__ vals,
                                                         unsigned* __restrict__ featbf,
                                                         short* __restrict__ Wbf,
                                                         int* __restrict__ deg,
                                                         unsigned* __restrict__ edata,
                                                         int4* __restrict__ ovf,
                                                         int* __restrict__ ovf_cnt,
                                                         int nPairs, int E, int nbB) {
    if ((int)blockIdx.x < nbB) {
        // ---- bucket specialist: entry = (nbr<<16) | bf16(val) ----
        int base = blockIdx.x * (256 * EPT) + threadIdx.x;
#pragma unroll
        for (int k = 0; k < EPT; k++) {
            int e = base + k * 256;            // coalesced per k-iteration
            if (e < E) {
                int t    = tgt[e];
                int slot = atomicAdd(&deg[t], 1);
                if (slot < CAP) {
                    unsigned ent = ((unsigned)nbr[e] << 16) |
                                   (unsigned)(unsigned short)f2bf(vals[e]);
                    edata[((unsigned)t << 5) + slot] = ent;
                } else {
                    int o = atomicAdd(ovf_cnt, 1);
                    int4 ov;
                    ov.x = t;
                    ov.y = nbr[e];
                    ov.z = __float_as_int(vals[e]);
                    ov.w = 0;
                    ovf[o] = ov;
                }
            }
        }
    } else {
        // ---- conv specialist ----
        int i = (blockIdx.x - nbB) * 256 + threadIdx.x;
        if (i < nPairs) {
            float2 f = ((const float2*)feat)[i];
            featbf[i] = packbf(f.x, f.y);
        }
        if (i < D * D) {
            Wbf[i]         = f2bf(W1[i]);
            Wbf[D * D + i] = f2bf(W2[i]);
        }
    }
}

// -------- gather + x1/x2 epilogue: one wave per node, uniform MLP-8 loop ---
// writes X1 = bf16(f + h), X2 = bf16(f * h) packed pairs
__global__ __launch_bounds__(256) void gather_kernel(const unsigned* __restrict__ featbf,
                                                     const unsigned* __restrict__ edata,
                                                     const int* __restrict__ deg,
                                                     const int4* __restrict__ ovf,
                                                     const int* __restrict__ ovf_cnt,
                                                     unsigned* __restrict__ X1,
                                                     unsigned* __restrict__ X2,
                                                     int nNodes) {
    int wid  = (blockIdx.x * 256 + threadIdx.x) >> 6;
    int lane = threadIdx.x & 63;
    if (wid >= nNodes) return;
    int d  = deg[wid];
    int dd = d < CAP ? d : CAP;   // edges present in edata

    unsigned uf = featbf[(long)wid * (D / 2) + lane];   // own row, hoisted

    float ax0 = 0.f, ay0 = 0.f, ax1 = 0.f, ay1 = 0.f;
    float ax2 = 0.f, ay2 = 0.f, ax3 = 0.f, ay3 = 0.f;

    {
        const unsigned* ep = edata + ((unsigned)wid << 5);
        int dm1 = dd - 1;
        // uniform loop: always 8 independent row loads in flight.
        for (int j = 0; j < dd; j += 8) {
            unsigned p0 = ep[min(j + 0, dm1)];
            unsigned p1 = ep[min(j + 1, dm1)];
            unsigned p2 = ep[min(j + 2, dm1)];
            unsigned p3 = ep[min(j + 3, dm1)];
            unsigned p4 = ep[min(j + 4, dm1)];
            unsigned p5 = ep[min(j + 5, dm1)];
            unsigned p6 = ep[min(j + 6, dm1)];
            unsigned p7 = ep[min(j + 7, dm1)];
            unsigned u0 = featbf[(long)(p0 >> 16) * (D / 2) + lane];
            unsigned u1 = featbf[(long)(p1 >> 16) * (D / 2) + lane];
            unsigned u2 = featbf[(long)(p2 >> 16) * (D / 2) + lane];
            unsigned u3 = featbf[(long)(p3 >> 16) * (D / 2) + lane];
            unsigned u4 = featbf[(long)(p4 >> 16) * (D / 2) + lane];
            unsigned u5 = featbf[(long)(p5 >> 16) * (D / 2) + lane];
            unsigned u6 = featbf[(long)(p6 >> 16) * (D / 2) + lane];
            unsigned u7 = featbf[(long)(p7 >> 16) * (D / 2) + lane];
            float v0 = (j + 0 < dd) ? bflo(p0) : 0.0f;
            float v1 = (j + 1 < dd) ? bflo(p1) : 0.0f;
            float v2 = (j + 2 < dd) ? bflo(p2) : 0.0f;
            float v3 = (j + 3 < dd) ? bflo(p3) : 0.0f;
            float v4 = (j + 4 < dd) ? bflo(p4) : 0.0f;
            float v5 = (j + 5 < dd) ? bflo(p5) : 0.0f;
            float v6 = (j + 6 < dd) ? bflo(p6) : 0.0f;
            float v7 = (j + 7 < dd) ? bflo(p7) : 0.0f;
            ax0 += bflo(u0) * v0; ay0 += bfhi(u0) * v0;
            ax1 += bflo(u1) * v1; ay1 += bfhi(u1) * v1;
            ax2 += bflo(u2) * v2; ay2 += bfhi(u2) * v2;
            ax3 += bflo(u3) * v3; ay3 += bfhi(u3) * v3;
            ax0 += bflo(u4) * v4; ay0 += bfhi(u4) * v4;
            ax1 += bflo(u5) * v5; ay1 += bfhi(u5) * v5;
            ax2 += bflo(u6) * v6; ay2 += bfhi(u6) * v6;
            ax3 += bflo(u7) * v7; ay3 += bfhi(u7) * v7;
        }
    }

    if (d > CAP) {
        // overflow edges live in the compact list (L2-hot, tiny)
        int cnt = *ovf_cnt;
        for (int basek = 0; basek < cnt; basek += 64) {
            int k = basek + lane;
            int t = (k < cnt) ? ovf[k].x : -1;
            unsigned long long m = __ballot(t == wid);
            while (m) {
                int b = __ffsll((long long)m) - 1;
                m &= m - 1;
                int4  ov = ovf[basek + b];
                float v  = __int_as_float(ov.z);
                unsigned u = featbf[(long)ov.y * (D / 2) + lane];
                ax0 += bflo(u) * v;
                ay0 += bfhi(u) * v;
            }
        }
    }

    float accx = (ax0 + ax1) + (ax2 + ax3);
    float accy = (ay0 + ay1) + (ay2 + ay3);
    float fx = bflo(uf), fy = bfhi(uf);
    X1[(long)wid * (D / 2) + lane] = packbf(fx + accx, fy + accy);
    X2[(long)wid * (D / 2) + lane] = packbf(fx * accx, fy * accy);
}

// -------- fused dual-GEMM + bias + leaky relu --------
// W staged in LDS (XOR-swizzled), amortized over 8 waves (512-thread block).
// One wave: 32 nodes x all 128 outs. MFMA operands SWAPPED (A=W, B=X) so
// each lane's 4 acc regs are 4 consecutive output cols -> float4 stores.
__global__ __launch_bounds__(512) void gemm_kernel(const short* __restrict__ X1s,
                                                   const short* __restrict__ X2s,
                                                   const short* __restrict__ Wbf,
                                                   const float* __restrict__ b1,
                                                   const float* __restrict__ b2,
                                                   float* __restrict__ out, int nNodes) {
    __shared__ __align__(16) short sW[2 * D * D];   // 64 KB

    int tid = threadIdx.x;
    // stage W: 4096 16-B chunks, XOR-swizzle chunk pos within row by row&15
    for (int c = tid; c < 4096; c += 512) {
        int r  = c >> 4;          // global row 0..255 (mat*128+row)
        int cc = c & 15;          // chunk within row
        int pp = cc ^ (r & 15);
        *(short8*)(&sW[r * D + pp * 8]) = *(const short8*)(Wbf + c * 8);
    }
    __syncthreads();

    int lane = tid & 63;
    int wid  = (blockIdx.x * 512 + tid) >> 6;
    int m0   = wid * 32;
    if (m0 >= nNodes) return;
    bool t2 = (m0 + 16) < nNodes;   // tiles are all-or-nothing (N % 16 == 0)

    int mrow = lane & 15;   // X-frag: node idx / W-frag: out-col idx / D: col idx
    int quad = lane >> 4;   // frags: k-group / D: row-group

    const short* xa1 = X1s + (long)(m0 + mrow) * D + quad * 8;        // tile 0
    const short* xa2 = X2s + (long)(m0 + mrow) * D + quad * 8;
    const short* xb1 = xa1 + 16 * D;                                  // tile 1
    const short* xb2 = xa2 + 16 * D;

    v4f acc[2][8];
#pragma unroll
    for (int t = 0; t < 2; t++)
#pragma unroll
        for (int i = 0; i < 8; i++) acc[t][i] = (v4f)(0.0f);

#pragma unroll
    for (int s = 0; s < 4; s++) {
        short8 a1 = *(const short8*)(xa1 + s * 32);
        short8 a2 = *(const short8*)(xa2 + s * 32);
        short8 c1, c2;
        if (t2) {
            c1 = *(const short8*)(xb1 + s * 32);
            c2 = *(const short8*)(xb2 + s * 32);
        }
        int pp = (s * 4 + quad) ^ mrow;   // swizzled chunk
#pragma unroll
        for (int ot = 0; ot < 8; ot++) {
            int row = ot * 16 + mrow;
            short8 w1 = *(const short8*)(&sW[row * D + pp * 8]);
            short8 w2 = *(const short8*)(&sW[D * D + row * D + pp * 8]);
            // swapped: A=W, B=X  ->  D[col=node, 4 regs = 4 consecutive o]
            acc[0][ot] = __builtin_amdgcn_mfma_f32_16x16x32_bf16(w1, a1, acc[0][ot], 0, 0, 0);
            acc[0][ot] = __builtin_amdgcn_mfma_f32_16x16x32_bf16(w2, a2, acc[0][ot], 0, 0, 0);
            if (t2) {
                acc[1][ot] = __builtin_amdgcn_mfma_f32_16x16x32_bf16(w1, c1, acc[1][ot], 0, 0, 0);
                acc[1][ot] = __builtin_amdgcn_mfma_f32_16x16x32_bf16(w2, c2, acc[1][ot], 0, 0, 0);
            }
        }
    }

    // epilogue: node = m0 + t*16 + mrow, o = ot*16 + quad*4 + r -> float4
    long n0 = (long)(m0 + mrow) * D;
    long n1 = (long)(m0 + 16 + mrow) * D;
#pragma unroll
    for (int ot = 0; ot < 8; ot++) {
        int o0 = ot * 16 + quad * 4;
        float4 bb1 = *(const float4*)(b1 + o0);
        float4 bb2 = *(const float4*)(b2 + o0);
        float4 v;
        v.x = lrelu(acc[0][ot][0] + bb1.x + bb2.x);
        v.y = lrelu(acc[0][ot][1] + bb1.y + bb2.y);
        v.z = lrelu(acc[0][ot][2] + bb1.z + bb2.z);
        v.w = lrelu(acc[0][ot][3] + bb1.w + bb2.w);
        *(float4*)(out + n0 + o0) = v;
        if (t2) {
            float4 w;
            w.x = lrelu(acc[1][ot][0] + bb1.x + bb2.x);
            w.y = lrelu(acc[1][ot][1] + bb1.y + bb2.y);
            w.z = lrelu(acc[1][ot][2] + bb1.z + bb2.z);
            w.w = lrelu(acc[1][ot][3] + bb1.w + bb2.w);
            *(float4*)(out + n1 + o0) = w;
        }
    }
}

extern "C" void kernel_launch(void* const* d_in, const int* in_sizes, int n_in,
                              void* d_out, int out_size, void* d_ws, size_t ws_size,
                              hipStream_t stream) {
    const float* feat = (const float*)d_in[0];
    const int*   tgt  = (const int*)d_in[1];
    const int*   nbr  = (const int*)d_in[2];
    const float* vals = (const float*)d_in[3];
    const float* W1   = (const float*)d_in[4];
    const float* b1   = (const float*)d_in[5];
    const float* W2   = (const float*)d_in[6];
    const float* b2   = (const float*)d_in[7];
    float*       out  = (float*)d_out;

    int E      = in_sizes[1];
    int nNodes = out_size / D;

    // ---- workspace layout ----
    int*      deg     = (int*)d_ws;                             // N (+4 incl ovf_cnt)
    int*      ovf_cnt = deg + nNodes;                           // 1 (inside memset range)
    int4*     ovf     = (int4*)(deg + nNodes + 4);              // E entries (16B-aligned)
    unsigned* edata   = (unsigned*)(ovf + E);                   // N*CAP u32
    short*    Wbf     = (short*)(edata + (long)nNodes * CAP);   // 2*D*D
    unsigned* featbf  = (unsigned*)(Wbf + 2 * D * D);           // N*D/2
    unsigned* X1      = featbf + (long)nNodes * (D / 2);        // N*D/2
    unsigned* X2      = X1 + (long)nNodes * (D / 2);            // N*D/2

    int nPairs = nNodes * (D / 2);
    int nbB    = (E + 256 * EPT - 1) / (256 * EPT);   // 306 bucket blocks
    int nbC    = (nPairs + 255) / 256;                // 12500 conv blocks

    hipMemsetAsync(deg, 0, (size_t)(nNodes + 4) * sizeof(int), stream);
    convbucket_kernel<<<nbB + nbC, 256, 0, stream>>>(feat, W1, W2, tgt, nbr, vals,
                                                     featbf, Wbf, deg, edata, ovf, ovf_cnt,
                                                     nPairs, E, nbB);
    gather_kernel<<<(nNodes * 64 + 255) / 256, 256, 0, stream>>>(featbf, edata, deg, ovf, ovf_cnt,
                                                                 X1, X2, nNodes);

    int nPairTiles = (nNodes + 31) / 32;               // 1563
    int nBlocks    = (nPairTiles + 7) / 8;             // 196 blocks of 8 waves
    gemm_kernel<<<nBlocks, 512, 0, stream>>>((const short*)X1, (const short*)X2, Wbf, b1, b2, out, nNodes);
}